// Round 1
// baseline (378.379 us; speedup 1.0000x reference)
//
#include <hip/hip_runtime.h>
#include <stdint.h>

typedef unsigned short u16;
typedef __attribute__((ext_vector_type(8))) short bf16x8;
typedef __attribute__((ext_vector_type(4))) float f32x4;

#define C_IN    64
#define K_OUT   128
#define HW      112
#define HW2     (HW * HW)   // 12544
#define CP      72          // padded channel pitch (bf16 elems): 16B-aligned rows, bank-spread
#define NW      114         // w' + 1 in [0,114): includes left/right zero pad
#define THREADS 256

// round-to-nearest-even fp32 -> bf16 (finite inputs)
__device__ __forceinline__ u16 f2bf(float f) {
  union { float f; uint32_t u; } x; x.f = f;
  return (u16)((x.u + 0x7FFFu + ((x.u >> 16) & 1u)) >> 16);
}

// OIHW fp32 weights -> bf16 wt[(rs*K_OUT + kout)*C_IN + c]  (c contiguous)
__global__ void prep_weights(const float* __restrict__ w, u16* __restrict__ wt) {
  int idx = blockIdx.x * 256 + threadIdx.x;
  if (idx >= K_OUT * C_IN * 9) return;
  int c    = idx & (C_IN - 1);
  int kout = (idx >> 6) & (K_OUT - 1);
  int rs   = idx >> 13;
  wt[idx] = f2bf(w[(kout * C_IN + c) * 9 + rs]);
}

// A-fragments (weights) live in registers: 4 bf16x8 live per rs-step, loaded
// straight from L2-resident wt. No Ws LDS, no barriers inside the rs loop.
// LDS = Xs only (49248 B) -> 3 blocks/CU if VGPR <= 168 (launch_bounds min 3).
__global__ __launch_bounds__(THREADS, 3) void conv3x3(
    const float* __restrict__ x, const u16* __restrict__ wt,
    const float* __restrict__ bias, float* __restrict__ out) {
  // X tile: [r][w'+1][c], bf16, c contiguous (pitch CP). 3*114*72*2 = 49248 B
  __shared__ u16 Xs[3][NW][CP];

  const int tid = threadIdx.x;

  // XCD-chunked swizzle: 3584 blocks % 8 XCDs == 0; each XCD gets 448
  // consecutive (n,h) rows -> adjacent-h blocks (sharing 2/3 input rows)
  // hit the same XCD L2.
  const int bid = blockIdx.x;
  const int lb  = (bid & 7) * 448 + (bid >> 3);
  const int n = lb / HW;
  const int h = lb % HW;

  // ---- zero only what the MFMA loop can read but staging never writes ----
  // pad columns w'=0 and w'=113, c in [0,64): 6 rows * 32 dwords = 192 dwords
  if (tid < 192) {
    const int seg  = tid >> 5;               // 0..5 -> (r, left/right)
    const int cd   = (tid & 31) * 2;         // c (even), dword-packed
    const int r    = seg >> 1;
    const int wcol = (seg & 1) ? (NW - 1) : 0;
    *(uint32_t*)&Xs[r][wcol][cd] = 0u;
  }
  // out-of-range h rows (block-uniform: only h==0 / h==111 blocks pay this)
  if (h == 0) {
    for (int t = tid; t < NW * 32; t += THREADS)
      *(uint32_t*)&Xs[0][t >> 5][(t & 31) * 2] = 0u;
  } else if (h == HW - 1) {
    for (int t = tid; t < NW * 32; t += THREADS)
      *(uint32_t*)&Xs[2][t >> 5][(t & 31) * 2] = 0u;
  }

  // ---- stage X rows h-1..h+1 as bf16 into [w'][c] ----
  // Task map: lane-major over channel-pair cp so a wave's 32 lanes write 32
  // distinct c at (near-)fixed w: LDS bank = (4w + cp) mod 32 -> exact 2-way
  // (free). Global side: 16B/lane gather across planes; every 64B line is
  // fully consumed by neighboring w4 tasks in this block -> no HBM over-fetch.
  const float* xn = x + (size_t)n * C_IN * HW2;
  for (int it = 0; it < 11; ++it) {
    const int task = tid + it * THREADS;     // 3 rows * 28 w4 * 32 cp = 2688
    if (task < 3 * 28 * 32) {
      const int cp   = task & 31;
      const int rest = task >> 5;            // 0..83
      const int w4   = rest % 28;
      const int r    = rest / 28;
      const int row  = h + r - 1;
      if (row >= 0 && row < HW) {
        const float* xrow = xn + (size_t)(2 * cp) * HW2 + (size_t)row * HW + w4 * 4;
        const float4 va = *(const float4*)(xrow);
        const float4 vb = *(const float4*)(xrow + HW2);
        const int wb = 1 + w4 * 4;
        const int c  = 2 * cp;
        *(uint32_t*)&Xs[r][wb + 0][c] = (uint32_t)f2bf(va.x) | ((uint32_t)f2bf(vb.x) << 16);
        *(uint32_t*)&Xs[r][wb + 1][c] = (uint32_t)f2bf(va.y) | ((uint32_t)f2bf(vb.y) << 16);
        *(uint32_t*)&Xs[r][wb + 2][c] = (uint32_t)f2bf(va.z) | ((uint32_t)f2bf(vb.z) << 16);
        *(uint32_t*)&Xs[r][wb + 3][c] = (uint32_t)f2bf(va.w) | ((uint32_t)f2bf(vb.w) << 16);
      }
    }
  }

  __syncthreads();  // the only barrier: staging + zero-fill complete

  const int lane = tid & 63;
  const int wave = tid >> 6;
  const int quad = lane >> 4;
  const int l15  = lane & 15;
  const int kb   = wave * 32;  // wave's kout base (32 channels per wave)

  f32x4 acc[2][7];
#pragma unroll
  for (int i = 0; i < 2; ++i)
#pragma unroll
    for (int j = 0; j < 7; ++j) acc[i][j] = (f32x4){0.f, 0.f, 0.f, 0.f};

  // 252 MFMAs + 126 ds_read_b128 + 36 16B global (L2) loads, zero barriers.
#pragma unroll
  for (int rs = 0; rs < 9; ++rs) {
    const int r = rs / 3;
    const int s = rs % 3;
    const u16* wbase = wt + rs * (K_OUT * C_IN);
#pragma unroll
    for (int ch = 0; ch < 2; ++ch) {
      const int c0 = ch * 32 + quad * 8;
      // A[m = l15][k = quad*8 + j] -> wt rows kb+mt*16+l15, c0..c0+7
      const bf16x8 a0 = *(const bf16x8*)(wbase + (kb + l15) * C_IN + c0);
      const bf16x8 a1 = *(const bf16x8*)(wbase + (kb + 16 + l15) * C_IN + c0);
#pragma unroll
      for (int w7 = 0; w7 < 7; ++w7) {
        // B[k = quad*8+j][nn = l15] -> Xs[r][w + s][c0..c0+7], w = w7*16+l15
        const bf16x8 b = *(const bf16x8*)&Xs[r][w7 * 16 + l15 + s][c0];
        acc[0][w7] = __builtin_amdgcn_mfma_f32_16x16x32_bf16(a0, b, acc[0][w7], 0, 0, 0);
        acc[1][w7] = __builtin_amdgcn_mfma_f32_16x16x32_bf16(a1, b, acc[1][w7], 0, 0, 0);
      }
    }
  }

  // ---- epilogue: D row = quad*4 + reg (kout), col = l15 (w) ----
  float* on = out + (size_t)n * K_OUT * HW2 + (size_t)h * HW;
#pragma unroll
  for (int mt = 0; mt < 2; ++mt) {
#pragma unroll
    for (int rg = 0; rg < 4; ++rg) {
      const int kout = kb + mt * 16 + quad * 4 + rg;
      const float bv = bias[kout];
      float* orow = on + (size_t)kout * HW2;
#pragma unroll
      for (int w7 = 0; w7 < 7; ++w7) {
        orow[w7 * 16 + l15] = acc[mt][w7][rg] + bv;
      }
    }
  }
}

extern "C" void kernel_launch(void* const* d_in, const int* in_sizes, int n_in,
                              void* d_out, int out_size, void* d_ws, size_t ws_size,
                              hipStream_t stream) {
  const float* x  = (const float*)d_in[0];
  const float* w  = (const float*)d_in[1];
  const float* bi = (const float*)d_in[2];
  float* out = (float*)d_out;
  u16* wt = (u16*)d_ws;  // needs 9*128*64*2 = 147456 B of scratch

  prep_weights<<<(K_OUT * C_IN * 9 + 255) / 256, 256, 0, stream>>>(w, wt);
  conv3x3<<<32 * HW, THREADS, 0, stream>>>(x, wt, bi, out);
}